// Round 2
// baseline (229.709 us; speedup 1.0000x reference)
//
#include <hip/hip_runtime.h>
#include <math.h>

#define N 512
#define C 157
#define M 20

__device__ __forceinline__ float sigmoidf_(float x) {
    return 1.0f / (1.0f + __expf(-x));
}

__global__ __launch_bounds__(256) void atf_main_kernel(
    const float* __restrict__ a,
    const float* __restrict__ aa,
    const float* __restrict__ target,
    const float* __restrict__ bank_values,
    const int* __restrict__ bank_times,
    const int* __restrict__ bank_mask,   // jax bool -> harness int32
    const int* __restrict__ ids,
    const int* __restrict__ times,
    float* __restrict__ out,        // qa [N*C]
    double* __restrict__ loss_acc)  // ws accumulator (zeroed before launch)
{
    const int n    = blockIdx.x;
    const int tid  = threadIdx.x;
    const int wave = tid >> 6;
    const int lane = tid & 63;

    __shared__ float s_ts[M];
    __shared__ int   s_mk[M];
    __shared__ float s_msg[C];
    __shared__ float s_fmsg[C];
    __shared__ float s_row[C];          // sum_j aa[i][j]*fmsg[j]
    __shared__ float s_colp[4][C];      // per-wave partial of sum_i aa[i][j]*msg[i]
    __shared__ float s_red[4];

    const int   id = ids[n];
    const float t0 = (float)times[n];

    if (tid < M) {
        s_ts[tid] = (float)bank_times[(size_t)id * M + tid];
        s_mk[tid] = (bank_mask[(size_t)id * M + tid] != 0) ? 1 : 0;
    }
    __syncthreads();

    // ---- phase 1: msg / fmsg (decay+kernel weighted averages) ----
    if (tid < C) {
        const float inv2s2 = 1.0f / (2.0f * 300.0f * 300.0f);
        const float INVDEC = 1.0f / 0.9f;
        float accP = 0.f, accF = 0.f, denP = 0.f, denF = 0.f;
        float wP = 1.f, wF = 1.f;
        const float* vb = bank_values + (size_t)id * M * C + tid;
        #pragma unroll
        for (int m = 0; m < M; ++m) {
            const float ts = s_ts[m];
            const float d  = ts - t0;
            const float kern = __expf(-d * d * inv2s2);
            const float v = vb[m * C];
            const bool mk = (s_mk[m] != 0);
            if (mk && ts < t0) { accP += wP * kern * v; denP += wP; wP *= INVDEC; }
            if (mk && ts > t0) { accF += wF * kern * v; denF += wF; wF *= INVDEC; }
        }
        s_msg[tid]  = (denP > 0.f) ? accP / fmaxf(denP, 1e-7f) : 0.0f;
        s_fmsg[tid] = (denF > 0.f) ? accF / fmaxf(denF, 1e-7f) : 0.0f;
    }
    __syncthreads();

    // ---- phase 2: single pass over aa[n] serving both einsums ----
    const float* aan = aa + (size_t)n * C * C;
    const int j0 = lane, j1 = lane + 64, j2 = lane + 128;
    float col0 = 0.f, col1 = 0.f, col2 = 0.f;
    const float f0 = s_fmsg[j0];
    const float f1 = (j1 < C) ? s_fmsg[j1] : 0.0f;
    const float f2 = (j2 < C) ? s_fmsg[j2] : 0.0f;

    for (int i = wave; i < C; i += 4) {
        const float* row = aan + i * C;
        const float mi = s_msg[i];
        const float v0 = row[j0];
        const float v1 = (j1 < C) ? row[j1] : 0.0f;
        const float v2 = (j2 < C) ? row[j2] : 0.0f;
        col0 += v0 * mi;
        col1 += v1 * mi;
        col2 += v2 * mi;
        float rp = v0 * f0 + v1 * f1 + v2 * f2;
        #pragma unroll
        for (int off = 32; off > 0; off >>= 1) rp += __shfl_down(rp, off, 64);
        if (lane == 0) s_row[i] = rp;
    }
    s_colp[wave][j0] = col0;
    if (j1 < C) s_colp[wave][j1] = col1;
    if (j2 < C) s_colp[wave][j2] = col2;
    __syncthreads();

    // ---- phase 3: epilogue, qa + BCE partials ----
    float local = 0.0f;
    if (tid < C) {
        const float colsum = s_colp[0][tid] + s_colp[1][tid] + s_colp[2][tid] + s_colp[3][tid];
        const float av = a[(size_t)n * C + tid];
        const float qlin = av + colsum + s_row[tid];
        const float p = sigmoidf_(qlin);
        out[(size_t)n * C + tid] = p;

        const float t = target[(size_t)n * C + tid];
        float pc = fminf(fmaxf(p, 1e-7f), 1.0f - 1e-7f);
        float pa = sigmoidf_(av);
        pa = fminf(fmaxf(pa, 1e-7f), 1.0f - 1e-7f);
        local = t * logf(pc) + (1.0f - t) * logf(1.0f - pc)
              + t * logf(pa) + (1.0f - t) * logf(1.0f - pa);
    }
    #pragma unroll
    for (int off = 32; off > 0; off >>= 1) local += __shfl_down(local, off, 64);
    if (lane == 0) s_red[wave] = local;
    __syncthreads();
    if (tid == 0) {
        const double s = (double)(s_red[0] + s_red[1] + s_red[2] + s_red[3]);
        atomicAdd(loss_acc, s);
    }
}

__global__ void atf_finalize_kernel(const double* __restrict__ loss_acc,
                                    float* __restrict__ out)
{
    // loss = ( -sum1/(N*C) + -sum2/(N*C) ) / 3 ; both sums already combined
    out[N * C] = (float)(-(*loss_acc) / ((double)(N * C) * 3.0));
}

extern "C" void kernel_launch(void* const* d_in, const int* in_sizes, int n_in,
                              void* d_out, int out_size, void* d_ws, size_t ws_size,
                              hipStream_t stream) {
    const float* a           = (const float*)d_in[0];
    const float* aa          = (const float*)d_in[1];
    const float* target      = (const float*)d_in[2];
    const float* bank_values = (const float*)d_in[3];
    const int*   bank_times  = (const int*)d_in[4];
    const int*   bank_mask   = (const int*)d_in[5];
    const int*   ids         = (const int*)d_in[6];
    const int*   times       = (const int*)d_in[7];

    float*  out      = (float*)d_out;
    double* loss_acc = (double*)d_ws;

    hipMemsetAsync(d_ws, 0, sizeof(double), stream);
    atf_main_kernel<<<N, 256, 0, stream>>>(a, aa, target, bank_values, bank_times,
                                           bank_mask, ids, times, out, loss_acc);
    atf_finalize_kernel<<<1, 1, 0, stream>>>(loss_acc, out);
}

// Round 3
// 218.958 us; speedup vs baseline: 1.0491x; 1.0491x over previous
//
#include <hip/hip_runtime.h>
#include <math.h>

#define N 512
#define C 157
#define M 20

__device__ __forceinline__ float sigmoidf_(float x) {
    return 1.0f / (1.0f + __expf(-x));
}
__device__ __forceinline__ float ntload(const float* p) {
    return __builtin_nontemporal_load(p);
}

__global__ __launch_bounds__(256) void atf_main_kernel(
    const float* __restrict__ a,
    const float* __restrict__ aa,
    const float* __restrict__ target,
    const float* __restrict__ bank_values,
    const int* __restrict__ bank_times,
    const int* __restrict__ bank_mask,   // jax bool -> harness int32
    const int* __restrict__ ids,
    const int* __restrict__ times,
    float* __restrict__ out,             // qa [N*C]
    float* __restrict__ loss_part)       // [N] per-block partials
{
    const int n    = blockIdx.x;
    const int tid  = threadIdx.x;
    const int wave = tid >> 6;
    const int lane = tid & 63;

    __shared__ float s_ts[M];
    __shared__ int   s_mk[M];
    __shared__ float s_msg[C];
    __shared__ float s_fmsg[C];
    __shared__ float s_row[C];          // sum_j aa[i][j]*fmsg[j]
    __shared__ float s_colp[4][C];      // per-wave partial of sum_i aa[i][j]*msg[i]
    __shared__ float s_red[4];

    const int   id = ids[n];
    const float t0 = (float)times[n];

    if (tid < M) {
        s_ts[tid] = (float)bank_times[(size_t)id * M + tid];
        s_mk[tid] = (bank_mask[(size_t)id * M + tid] != 0) ? 1 : 0;
    }
    __syncthreads();

    // ---- phase 1: msg / fmsg (decay+kernel weighted averages) ----
    if (tid < C) {
        const float inv2s2 = 1.0f / (2.0f * 300.0f * 300.0f);
        const float INVDEC = 1.0f / 0.9f;
        float accP = 0.f, accF = 0.f, denP = 0.f, denF = 0.f;
        float wP = 1.f, wF = 1.f;
        const float* vb = bank_values + (size_t)id * M * C + tid;
        #pragma unroll
        for (int m = 0; m < M; ++m) {
            const float ts = s_ts[m];
            const float d  = ts - t0;
            const float kern = __expf(-d * d * inv2s2);
            const float v = vb[m * C];
            const bool mk = (s_mk[m] != 0);
            if (mk && ts < t0) { accP += wP * kern * v; denP += wP; wP *= INVDEC; }
            if (mk && ts > t0) { accF += wF * kern * v; denF += wF; wF *= INVDEC; }
        }
        s_msg[tid]  = (denP > 0.f) ? accP / fmaxf(denP, 1e-7f) : 0.0f;
        s_fmsg[tid] = (denF > 0.f) ? accF / fmaxf(denF, 1e-7f) : 0.0f;
    }
    __syncthreads();

    // ---- phase 2: single pass over aa[n] serving both einsums, 2 rows/iter ----
    const float* aan = aa + (size_t)n * C * C;
    const int j0 = lane, j1 = lane + 64, j2 = lane + 128;
    float col0 = 0.f, col1 = 0.f, col2 = 0.f;
    const float f0 = s_fmsg[j0];
    const float f1 = (j1 < C) ? s_fmsg[j1] : 0.0f;
    const float f2 = (j2 < C) ? s_fmsg[j2] : 0.0f;
    const bool ok1 = (j1 < C), ok2 = (j2 < C);

    for (int i = wave; i < C; i += 8) {
        const int ib = i + 4;
        const float* rowA = aan + i * C;
        const float mA = s_msg[i];
        const float a0 = ntload(rowA + j0);
        const float a1 = ok1 ? ntload(rowA + j1) : 0.0f;
        const float a2 = ok2 ? ntload(rowA + j2) : 0.0f;

        float b0 = 0.f, b1 = 0.f, b2 = 0.f, mB = 0.f;
        if (ib < C) {
            const float* rowB = aan + ib * C;
            mB = s_msg[ib];
            b0 = ntload(rowB + j0);
            b1 = ok1 ? ntload(rowB + j1) : 0.0f;
            b2 = ok2 ? ntload(rowB + j2) : 0.0f;
        }

        col0 += a0 * mA + b0 * mB;
        col1 += a1 * mA + b1 * mB;
        col2 += a2 * mA + b2 * mB;

        float rpA = a0 * f0 + a1 * f1 + a2 * f2;
        float rpB = b0 * f0 + b1 * f1 + b2 * f2;
        #pragma unroll
        for (int off = 32; off > 0; off >>= 1) {
            rpA += __shfl_down(rpA, off, 64);
            rpB += __shfl_down(rpB, off, 64);
        }
        if (lane == 0) {
            s_row[i] = rpA;
            if (ib < C) s_row[ib] = rpB;
        }
    }
    s_colp[wave][j0] = col0;
    if (ok1) s_colp[wave][j1] = col1;
    if (ok2) s_colp[wave][j2] = col2;
    __syncthreads();

    // ---- phase 3: epilogue, qa + BCE partials ----
    float local = 0.0f;
    if (tid < C) {
        const float colsum = s_colp[0][tid] + s_colp[1][tid] + s_colp[2][tid] + s_colp[3][tid];
        const float av = a[(size_t)n * C + tid];
        const float qlin = av + colsum + s_row[tid];
        const float p = sigmoidf_(qlin);
        out[(size_t)n * C + tid] = p;

        const float t = target[(size_t)n * C + tid];
        float pc = fminf(fmaxf(p, 1e-7f), 1.0f - 1e-7f);
        float pa = sigmoidf_(av);
        pa = fminf(fmaxf(pa, 1e-7f), 1.0f - 1e-7f);
        local = t * logf(pc) + (1.0f - t) * logf(1.0f - pc)
              + t * logf(pa) + (1.0f - t) * logf(1.0f - pa);
    }
    #pragma unroll
    for (int off = 32; off > 0; off >>= 1) local += __shfl_down(local, off, 64);
    if (lane == 0) s_red[wave] = local;
    __syncthreads();
    if (tid == 0) {
        loss_part[n] = s_red[0] + s_red[1] + s_red[2] + s_red[3];
    }
}

__global__ __launch_bounds__(256) void atf_finalize_kernel(
    const float* __restrict__ loss_part,
    float* __restrict__ out)
{
    const int tid  = threadIdx.x;
    const int wave = tid >> 6;
    const int lane = tid & 63;
    __shared__ double s_red[4];

    double local = (double)loss_part[tid] + (double)loss_part[tid + 256];
    #pragma unroll
    for (int off = 32; off > 0; off >>= 1) local += __shfl_down(local, off, 64);
    if (lane == 0) s_red[wave] = local;
    __syncthreads();
    if (tid == 0) {
        const double s = s_red[0] + s_red[1] + s_red[2] + s_red[3];
        out[N * C] = (float)(-s / ((double)(N * C) * 3.0));
    }
}

extern "C" void kernel_launch(void* const* d_in, const int* in_sizes, int n_in,
                              void* d_out, int out_size, void* d_ws, size_t ws_size,
                              hipStream_t stream) {
    const float* a           = (const float*)d_in[0];
    const float* aa          = (const float*)d_in[1];
    const float* target      = (const float*)d_in[2];
    const float* bank_values = (const float*)d_in[3];
    const int*   bank_times  = (const int*)d_in[4];
    const int*   bank_mask   = (const int*)d_in[5];
    const int*   ids         = (const int*)d_in[6];
    const int*   times       = (const int*)d_in[7];

    float* out       = (float*)d_out;
    float* loss_part = (float*)d_ws;   // 512 floats

    atf_main_kernel<<<N, 256, 0, stream>>>(a, aa, target, bank_values, bank_times,
                                           bank_mask, ids, times, out, loss_part);
    atf_finalize_kernel<<<1, 256, 0, stream>>>(loss_part, out);
}

// Round 4
// 204.810 us; speedup vs baseline: 1.1216x; 1.0691x over previous
//
#include <hip/hip_runtime.h>
#include <math.h>

#define N 512
#define C 157
#define M 20
#define NW 8   // waves per block (512 threads)

__device__ __forceinline__ float sigmoidf_(float x) {
    return 1.0f / (1.0f + __expf(-x));
}
__device__ __forceinline__ float ntload(const float* p) {
    return __builtin_nontemporal_load(p);
}

__global__ __launch_bounds__(512) void atf_main_kernel(
    const float* __restrict__ a,
    const float* __restrict__ aa,
    const float* __restrict__ target,
    const float* __restrict__ bank_values,
    const int* __restrict__ bank_times,
    const int* __restrict__ bank_mask,   // jax bool -> harness int32
    const int* __restrict__ ids,
    const int* __restrict__ times,
    float* __restrict__ out,             // qa [N*C]
    float* __restrict__ loss_part)       // [N] per-block partials
{
    const int n    = blockIdx.x;
    const int tid  = threadIdx.x;
    const int wave = tid >> 6;
    const int lane = tid & 63;

    __shared__ float s_ts[M];
    __shared__ int   s_mk[M];
    __shared__ float s_msg[C];
    __shared__ float s_fmsg[C];
    __shared__ float s_row[C];           // sum_j aa[i][j]*fmsg[j]
    __shared__ float s_colp[NW][C];      // per-wave partial of sum_i aa[i][j]*msg[i]
    __shared__ float s_red[NW];

    const int   id = ids[n];
    const float t0 = (float)times[n];

    if (tid < M) {
        s_ts[tid] = (float)bank_times[(size_t)id * M + tid];
        s_mk[tid] = (bank_mask[(size_t)id * M + tid] != 0) ? 1 : 0;
    }
    __syncthreads();

    // ---- phase 1: msg / fmsg (decay+kernel weighted averages) ----
    if (tid < C) {
        const float inv2s2 = 1.0f / (2.0f * 300.0f * 300.0f);
        const float INVDEC = 1.0f / 0.9f;
        float accP = 0.f, accF = 0.f, denP = 0.f, denF = 0.f;
        float wP = 1.f, wF = 1.f;
        const float* vb = bank_values + (size_t)id * M * C + tid;
        #pragma unroll
        for (int m = 0; m < M; ++m) {
            const float ts = s_ts[m];
            const float d  = ts - t0;
            const float kern = __expf(-d * d * inv2s2);
            const float v = vb[m * C];
            const bool mk = (s_mk[m] != 0);
            if (mk && ts < t0) { accP += wP * kern * v; denP += wP; wP *= INVDEC; }
            if (mk && ts > t0) { accF += wF * kern * v; denF += wF; wF *= INVDEC; }
        }
        s_msg[tid]  = (denP > 0.f) ? accP / fmaxf(denP, 1e-7f) : 0.0f;
        s_fmsg[tid] = (denF > 0.f) ? accF / fmaxf(denF, 1e-7f) : 0.0f;
    }
    __syncthreads();

    // ---- phase 2: single pass over aa[n] serving both einsums, 2 rows/iter/wave ----
    const float* aan = aa + (size_t)n * C * C;
    const int j0 = lane, j1 = lane + 64, j2 = lane + 128;
    float col0 = 0.f, col1 = 0.f, col2 = 0.f;
    const bool ok1 = (j1 < C), ok2 = (j2 < C);
    const float f0 = s_fmsg[j0];
    const float f1 = ok1 ? s_fmsg[j1] : 0.0f;
    const float f2 = ok2 ? s_fmsg[j2] : 0.0f;

    for (int i = wave; i < C; i += 2 * NW) {
        const int ib = i + NW;
        const float* rowA = aan + i * C;
        const float mA = s_msg[i];
        const float a0 = ntload(rowA + j0);
        const float a1 = ok1 ? ntload(rowA + j1) : 0.0f;
        const float a2 = ok2 ? ntload(rowA + j2) : 0.0f;

        float b0 = 0.f, b1 = 0.f, b2 = 0.f, mB = 0.f;
        if (ib < C) {
            const float* rowB = aan + ib * C;
            mB = s_msg[ib];
            b0 = ntload(rowB + j0);
            b1 = ok1 ? ntload(rowB + j1) : 0.0f;
            b2 = ok2 ? ntload(rowB + j2) : 0.0f;
        }

        col0 += a0 * mA + b0 * mB;
        col1 += a1 * mA + b1 * mB;
        col2 += a2 * mA + b2 * mB;

        float rpA = a0 * f0 + a1 * f1 + a2 * f2;
        float rpB = b0 * f0 + b1 * f1 + b2 * f2;
        #pragma unroll
        for (int off = 32; off > 0; off >>= 1) {
            rpA += __shfl_down(rpA, off, 64);
            rpB += __shfl_down(rpB, off, 64);
        }
        if (lane == 0) {
            s_row[i] = rpA;
            if (ib < C) s_row[ib] = rpB;
        }
    }
    s_colp[wave][j0] = col0;
    if (ok1) s_colp[wave][j1] = col1;
    if (ok2) s_colp[wave][j2] = col2;
    __syncthreads();

    // ---- phase 3: epilogue, qa + BCE partials ----
    float local = 0.0f;
    if (tid < C) {
        float colsum = 0.0f;
        #pragma unroll
        for (int w = 0; w < NW; ++w) colsum += s_colp[w][tid];
        const float av = a[(size_t)n * C + tid];
        const float qlin = av + colsum + s_row[tid];
        const float p = sigmoidf_(qlin);
        out[(size_t)n * C + tid] = p;

        const float t = target[(size_t)n * C + tid];
        float pc = fminf(fmaxf(p, 1e-7f), 1.0f - 1e-7f);
        float pa = sigmoidf_(av);
        pa = fminf(fmaxf(pa, 1e-7f), 1.0f - 1e-7f);
        local = t * logf(pc) + (1.0f - t) * logf(1.0f - pc)
              + t * logf(pa) + (1.0f - t) * logf(1.0f - pa);
    }
    #pragma unroll
    for (int off = 32; off > 0; off >>= 1) local += __shfl_down(local, off, 64);
    if (lane == 0) s_red[wave] = local;
    __syncthreads();
    if (tid == 0) {
        float s = 0.0f;
        #pragma unroll
        for (int w = 0; w < NW; ++w) s += s_red[w];
        loss_part[n] = s;
    }
}

__global__ __launch_bounds__(256) void atf_finalize_kernel(
    const float* __restrict__ loss_part,
    float* __restrict__ out)
{
    const int tid  = threadIdx.x;
    const int wave = tid >> 6;
    const int lane = tid & 63;
    __shared__ double s_red[4];

    double local = (double)loss_part[tid] + (double)loss_part[tid + 256];
    #pragma unroll
    for (int off = 32; off > 0; off >>= 1) local += __shfl_down(local, off, 64);
    if (lane == 0) s_red[wave] = local;
    __syncthreads();
    if (tid == 0) {
        const double s = s_red[0] + s_red[1] + s_red[2] + s_red[3];
        out[N * C] = (float)(-s / ((double)(N * C) * 3.0));
    }
}

extern "C" void kernel_launch(void* const* d_in, const int* in_sizes, int n_in,
                              void* d_out, int out_size, void* d_ws, size_t ws_size,
                              hipStream_t stream) {
    const float* a           = (const float*)d_in[0];
    const float* aa          = (const float*)d_in[1];
    const float* target      = (const float*)d_in[2];
    const float* bank_values = (const float*)d_in[3];
    const int*   bank_times  = (const int*)d_in[4];
    const int*   bank_mask   = (const int*)d_in[5];
    const int*   ids         = (const int*)d_in[6];
    const int*   times       = (const int*)d_in[7];

    float* out       = (float*)d_out;
    float* loss_part = (float*)d_ws;   // 512 floats

    atf_main_kernel<<<N, 512, 0, stream>>>(a, aa, target, bank_values, bank_times,
                                           bank_mask, ids, times, out, loss_part);
    atf_finalize_kernel<<<1, 256, 0, stream>>>(loss_part, out);
}